// Round 3
// baseline (362.851 us; speedup 1.0000x reference)
//
#include <hip/hip_runtime.h>

#define N_NODES_C 50000
#define F_IN_C 64
#define HID_C 128
#define N_GRAPHS_C 500
#define N_CLS_C 10
#define MLP_HID_C 50
#define ZROW N_NODES_C   // zero row index in compressed x

__device__ __forceinline__ float bl_f(float v, int l) {
    return __uint_as_float(__builtin_amdgcn_readlane(__float_as_uint(v), l));
}

// round-to-nearest-even bf16 pack of two floats -> (lo=a, hi=b)
__device__ __forceinline__ unsigned pk_bf16(float a, float b) {
    unsigned ua = __float_as_uint(a), ub = __float_as_uint(b);
    ua += 0x7FFFu + ((ua >> 16) & 1u);
    ub += 0x7FFFu + ((ub >> 16) & 1u);
    return (ua >> 16) | (ub & 0xFFFF0000u);
}

// ---------------------------------------------------------------------------
// Prep (fused): degree histogram + bf16-compress x (+ zero row) + graph bounds
// ---------------------------------------------------------------------------
__global__ __launch_bounds__(256) void prep_kernel(
    const float* __restrict__ x,
    const int* __restrict__ dst,
    const int* __restrict__ batch,
    int* __restrict__ deg_i,
    unsigned* __restrict__ xh,
    int* __restrict__ start,
    int n_edges)
{
    int tid = blockIdx.x * 256 + threadIdx.x;
    int stride = gridDim.x * 256;

    for (int e = tid; e < n_edges; e += stride)
        atomicAdd(&deg_i[dst[e]], 1);

    const float2* xf2 = (const float2*)x;
    int nx = N_NODES_C * (F_IN_C / 2);
    int total = (N_NODES_C + 1) * (F_IN_C / 2);
    for (int i = tid; i < total; i += stride) {
        if (i < nx) { float2 v = xf2[i]; xh[i] = pk_bf16(v.x, v.y); }
        else        xh[i] = 0u;
    }

    for (int i = tid; i < N_NODES_C; i += stride) {
        int b = batch[i];
        if (i == 0) { for (int g = 0; g <= b; ++g) start[g] = 0; }
        else { int p = batch[i - 1]; for (int g = p + 1; g <= b; ++g) start[g] = i; }
        if (i == N_NODES_C - 1) { for (int g = b + 1; g <= N_GRAPHS_C; ++g) start[g] = N_NODES_C; }
    }
}

// ---------------------------------------------------------------------------
// Single-block exclusive scan of degrees -> off[] and cursor[] (scatter base)
// ---------------------------------------------------------------------------
__global__ __launch_bounds__(1024) void scan_kernel(
    const int* __restrict__ deg_i,
    int* __restrict__ off,
    int* __restrict__ cursor)
{
    __shared__ int s[1024];
    const int CH = (N_NODES_C + 1023) / 1024;   // 49
    int t = threadIdx.x;
    int base = t * CH;
    int sum = 0;
    for (int j = 0; j < CH; ++j) {
        int i = base + j;
        if (i < N_NODES_C) sum += deg_i[i];
    }
    s[t] = sum;
    __syncthreads();
    for (int o = 1; o < 1024; o <<= 1) {
        int v = (t >= o) ? s[t - o] : 0;
        __syncthreads();
        s[t] += v;
        __syncthreads();
    }
    int run = (t > 0) ? s[t - 1] : 0;
    for (int j = 0; j < CH; ++j) {
        int i = base + j;
        if (i < N_NODES_C) {
            off[i] = run;
            cursor[i] = run;
            run += deg_i[i];
        }
    }
    if (t == 1023) off[N_NODES_C] = s[1023];
}

// ---------------------------------------------------------------------------
// Scatter edge sources into CSR adjacency
// ---------------------------------------------------------------------------
__global__ __launch_bounds__(256) void scatter_kernel(
    const int* __restrict__ src, const int* __restrict__ dst,
    int* __restrict__ cursor, int* __restrict__ adj, int n_edges)
{
    int e = blockIdx.x * 256 + threadIdx.x;
    if (e >= n_edges) return;
    int p = atomicAdd(&cursor[dst[e]], 1);
    adj[p] = src[e];
}

// ---------------------------------------------------------------------------
// Fused gather + linear. Wave = 2 nodes. Gather: lane -> (edge-slot g=lane>>3,
// feat-octet s=lane&7); each lane loads uint4 = 8 bf16 feats; 8 edges per load
// instr; tails read cached zero-row. Cross-slot reduce via shfl_xor(8/16/32).
// Matmul: W packed bf16-pairs in 32KB LDS; per k one ds_read_b32 serves both
// output halves; node values broadcast via compile-time readlane.
// ---------------------------------------------------------------------------
__global__ __launch_bounds__(512) void gather_emb_kernel(
    const float* __restrict__ x,
    const uint4* __restrict__ xh4,     // (N+1) rows of 8 x uint4
    const int* __restrict__ adj,
    const int* __restrict__ off,
    const int* __restrict__ deg_i,
    const float* __restrict__ Wn,
    const float* __restrict__ Ws,
    const float* __restrict__ bias,
    float* __restrict__ emb_out)
{
    __shared__ unsigned sWp[128 * 64];   // 32KB: pack(W[k][lane], W[k][64+lane])
    int t = threadIdx.x;
    for (int i = t; i < 128 * 64; i += 512) {
        int k = i >> 6, lane = i & 63;
        float w0, w1;
        if (k < 64) { w0 = Wn[k * 128 + lane]; w1 = Wn[k * 128 + 64 + lane]; }
        else        { w0 = Ws[(k - 64) * 128 + lane]; w1 = Ws[(k - 64) * 128 + 64 + lane]; }
        sWp[i] = pk_bf16(w0, w1);
    }
    __syncthreads();

    int wave = t >> 6, lane = t & 63;
    int nb = (blockIdx.x * 8 + wave) * 2;        // grid exact: covers [0,50000)
    int s = lane & 7, g = lane >> 3;

    float2 a0[4], a1[4];

    auto gather = [&](int node, float2* acc) {
        #pragma unroll
        for (int p = 0; p < 4; ++p) acc[p] = make_float2(0.f, 0.f);
        int o = off[node];
        int d = deg_i[node];
        for (int j0 = 0; j0 < d; j0 += 8) {
            int nid = (j0 + g < d) ? adj[o + j0 + g] : ZROW;
            uint4 w = xh4[(size_t)nid * 8 + s];
            acc[0].x += __uint_as_float(w.x << 16);
            acc[0].y += __uint_as_float(w.x & 0xFFFF0000u);
            acc[1].x += __uint_as_float(w.y << 16);
            acc[1].y += __uint_as_float(w.y & 0xFFFF0000u);
            acc[2].x += __uint_as_float(w.z << 16);
            acc[2].y += __uint_as_float(w.z & 0xFFFF0000u);
            acc[3].x += __uint_as_float(w.w << 16);
            acc[3].y += __uint_as_float(w.w & 0xFFFF0000u);
        }
        #pragma unroll
        for (int m = 8; m <= 32; m <<= 1) {
            #pragma unroll
            for (int p = 0; p < 4; ++p) {
                acc[p].x += __shfl_xor(acc[p].x, m, 64);
                acc[p].y += __shfl_xor(acc[p].y, m, 64);
            }
        }
        float inv = 1.0f / fmaxf((float)d, 1.0f);
        #pragma unroll
        for (int p = 0; p < 4; ++p) { acc[p].x *= inv; acc[p].y *= inv; }
    };
    gather(nb, a0);
    gather(nb + 1, a1);

    float xs0 = x[(size_t)nb * F_IN_C + lane];
    float xs1 = x[(size_t)(nb + 1) * F_IN_C + lane];
    float bl = bias[lane], bh = bias[64 + lane];
    float al0 = bl, ah0 = bh, al1 = bl, ah1 = bh;

    // agg @ Wn : feat k of node i lives in reg pair (k&7)>>1, comp k&1, lane k>>3
    #pragma unroll
    for (int k = 0; k < 64; ++k) {
        unsigned u = sWp[k * 64 + lane];
        float wlo = __uint_as_float(u << 16);
        float whi = __uint_as_float(u & 0xFFFF0000u);
        float v0 = bl_f((k & 1) ? a0[(k & 7) >> 1].y : a0[(k & 7) >> 1].x, k >> 3);
        float v1 = bl_f((k & 1) ? a1[(k & 7) >> 1].y : a1[(k & 7) >> 1].x, k >> 3);
        al0 += v0 * wlo; ah0 += v0 * whi;
        al1 += v1 * wlo; ah1 += v1 * whi;
    }
    // x @ Ws : self row in lane=feature layout
    #pragma unroll
    for (int k = 0; k < 64; ++k) {
        unsigned u = sWp[(64 + k) * 64 + lane];
        float wlo = __uint_as_float(u << 16);
        float whi = __uint_as_float(u & 0xFFFF0000u);
        float v0 = bl_f(xs0, k);
        float v1 = bl_f(xs1, k);
        al0 += v0 * wlo; ah0 += v0 * whi;
        al1 += v1 * wlo; ah1 += v1 * whi;
    }

    emb_out[(size_t)nb * HID_C + lane]            = al0;
    emb_out[(size_t)nb * HID_C + 64 + lane]       = ah0;
    emb_out[(size_t)(nb + 1) * HID_C + lane]      = al1;
    emb_out[(size_t)(nb + 1) * HID_C + 64 + lane] = ah1;
}

// ---------------------------------------------------------------------------
// Segment mean-pool of relu(emb), float4-vectorized, no atomics.
// ---------------------------------------------------------------------------
__global__ __launch_bounds__(256) void pool_kernel(
    const float* __restrict__ emb, const int* __restrict__ start,
    float* __restrict__ pooled)
{
    int gph = blockIdx.x;
    int t = threadIdx.x;
    int q = t & 31;        // feat quad
    int r0 = t >> 5;       // row slot 0..7
    int s0 = start[gph], e0 = start[gph + 1];
    const float4* e4 = (const float4*)emb;   // row = 32 float4
    float4 acc = make_float4(0.f, 0.f, 0.f, 0.f);
    for (int r = s0 + r0; r < e0; r += 8) {
        float4 v = e4[(size_t)r * 32 + q];
        acc.x += fmaxf(v.x, 0.f); acc.y += fmaxf(v.y, 0.f);
        acc.z += fmaxf(v.z, 0.f); acc.w += fmaxf(v.w, 0.f);
    }
    __shared__ float4 sh[256];
    sh[t] = acc;
    __syncthreads();
    if (t < 32) {
        float4 a = sh[t];
        #pragma unroll
        for (int r = 1; r < 8; ++r) {
            float4 b = sh[t + 32 * r];
            a.x += b.x; a.y += b.y; a.z += b.z; a.w += b.w;
        }
        float inv = 1.0f / fmaxf((float)(e0 - s0), 1.0f);
        float4* pp = (float4*)pooled;
        pp[(size_t)gph * 32 + t] = make_float4(a.x * inv, a.y * inv, a.z * inv, a.w * inv);
    }
}

// ---------------------------------------------------------------------------
// Per-graph MLP head + log_softmax.
// ---------------------------------------------------------------------------
__global__ __launch_bounds__(64) void mlp_head_kernel(
    const float* __restrict__ pooled,
    const float* __restrict__ W1,
    const float* __restrict__ b1,
    const float* __restrict__ W2,
    const float* __restrict__ b2,
    float* __restrict__ logits_out)
{
    int g = blockIdx.x;
    int t = threadIdx.x;
    __shared__ float sp[HID_C];
    __shared__ float sh[MLP_HID_C];
    __shared__ float sl[N_CLS_C];

    sp[t] = pooled[(size_t)g * HID_C + t];
    sp[t + 64] = pooled[(size_t)g * HID_C + t + 64];
    __syncthreads();

    if (t < MLP_HID_C) {
        float a = b1[t];
        #pragma unroll 8
        for (int k = 0; k < HID_C; ++k) a += sp[k] * W1[k * MLP_HID_C + t];
        sh[t] = fmaxf(a, 0.0f);
    }
    __syncthreads();

    if (t < N_CLS_C) {
        float a = b2[t];
        #pragma unroll
        for (int k = 0; k < MLP_HID_C; ++k) a += sh[k] * W2[k * N_CLS_C + t];
        sl[t] = a;
    }
    __syncthreads();

    if (t < N_CLS_C) {
        float m = sl[0];
        #pragma unroll
        for (int i = 1; i < N_CLS_C; ++i) m = fmaxf(m, sl[i]);
        float sum = 0.0f;
        #pragma unroll
        for (int i = 0; i < N_CLS_C; ++i) sum += expf(sl[i] - m);
        logits_out[(size_t)g * N_CLS_C + t] = sl[t] - m - logf(sum);
    }
}

extern "C" void kernel_launch(void* const* d_in, const int* in_sizes, int n_in,
                              void* d_out, int out_size, void* d_ws, size_t ws_size,
                              hipStream_t stream) {
    const float* x      = (const float*)d_in[0];
    const int*   ei     = (const int*)d_in[1];
    const int*   batch  = (const int*)d_in[2];
    const float* Wn     = (const float*)d_in[3];
    const float* Ws     = (const float*)d_in[4];
    const float* bias   = (const float*)d_in[5];
    const float* W1     = (const float*)d_in[6];
    const float* b1     = (const float*)d_in[7];
    const float* W2     = (const float*)d_in[8];
    const float* b2     = (const float*)d_in[9];

    float* out = (float*)d_out;
    int n_edges = in_sizes[1] / 2;
    const int* src = ei;
    const int* dst = ei + n_edges;

    // workspace layout:
    //   xh[(N+1)*32 uints] (16B-aligned at base) | deg_i[N] | off[N+1] |
    //   cursor[N] | start[G+1] | adj[E+8] | pooled[G*128 floats]
    unsigned* xh   = (unsigned*)d_ws;
    size_t xh_u    = (size_t)(N_NODES_C + 1) * (F_IN_C / 2);   // 1,600,032 uints
    int* deg_i     = (int*)d_ws + xh_u;
    int* off       = deg_i + N_NODES_C;
    int* cursor    = off + (N_NODES_C + 1);
    int* start     = cursor + N_NODES_C;
    int* adj       = start + (N_GRAPHS_C + 1);
    float* pooled  = (float*)(adj + n_edges + 8);

    // zero only deg_i (hist accumulates into it)
    hipMemsetAsync(deg_i, 0, (size_t)N_NODES_C * sizeof(int), stream);

    prep_kernel<<<1024, 256, 0, stream>>>(x, dst, batch, deg_i, xh, start, n_edges);
    scan_kernel<<<1, 1024, 0, stream>>>(deg_i, off, cursor);
    scatter_kernel<<<(n_edges + 255) / 256, 256, 0, stream>>>(src, dst, cursor, adj, n_edges);

    // 3125 blocks x 8 waves x 2 nodes = 50000 nodes exactly
    gather_emb_kernel<<<3125, 512, 0, stream>>>(x, (const uint4*)xh, adj, off, deg_i,
                                                Wn, Ws, bias, out);

    pool_kernel<<<N_GRAPHS_C, 256, 0, stream>>>(out, start, pooled);
    mlp_head_kernel<<<N_GRAPHS_C, 64, 0, stream>>>(pooled, W1, b1, W2, b2,
                                                   out + (size_t)N_NODES_C * HID_C);
}

// Round 4
// 154.677 us; speedup vs baseline: 2.3459x; 2.3459x over previous
//
#include <hip/hip_runtime.h>

#define N_NODES_C 50000
#define F_IN_C 64
#define HID_C 128
#define N_GRAPHS_C 500
#define N_CLS_C 10
#define MLP_HID_C 50
#define SCAN_TILE 1024
#define N_SCAN_BLK ((N_NODES_C + SCAN_TILE - 1) / SCAN_TILE)   // 49

__device__ __forceinline__ float bl_f(float v, int l) {
    return __uint_as_float(__builtin_amdgcn_readlane(__float_as_uint(v), l));
}
__device__ __forceinline__ int bl_i(int v, int l) {
    return __builtin_amdgcn_readlane(v, l);
}
// round-to-nearest-even bf16 pack of two floats -> (lo=a, hi=b)
__device__ __forceinline__ unsigned pk_bf16(float a, float b) {
    unsigned ua = __float_as_uint(a), ub = __float_as_uint(b);
    ua += 0x7FFFu + ((ua >> 16) & 1u);
    ub += 0x7FFFu + ((ub >> 16) & 1u);
    return (ua >> 16) | (ub & 0xFFFF0000u);
}

// ---------------------------------------------------------------------------
// Stage 1: degree histogram + per-edge rank (makes scatter atomic-free).
// Also computes graph bounds from sorted batch (independent work, same pass).
// ---------------------------------------------------------------------------
__global__ __launch_bounds__(256) void hist_kernel(
    const int* __restrict__ dst,
    const int* __restrict__ batch,
    int* __restrict__ deg_i,
    int* __restrict__ rank,
    int* __restrict__ start,
    int n_edges)
{
    int tid = blockIdx.x * 256 + threadIdx.x;
    int stride = gridDim.x * 256;
    for (int e = tid; e < n_edges; e += stride)
        rank[e] = atomicAdd(&deg_i[dst[e]], 1);
    for (int i = tid; i < N_NODES_C; i += stride) {
        int b = batch[i];
        if (i == 0) { for (int g = 0; g <= b; ++g) start[g] = 0; }
        else { int p = batch[i - 1]; for (int g = p + 1; g <= b; ++g) start[g] = i; }
        if (i == N_NODES_C - 1) { for (int g = b + 1; g <= N_GRAPHS_C; ++g) start[g] = N_NODES_C; }
    }
}

// Stage 2a: per-1024-tile sums
__global__ __launch_bounds__(256) void scan1_kernel(
    const int* __restrict__ deg_i, int* __restrict__ bsums, int n)
{
    __shared__ int s[256];
    int base = blockIdx.x * SCAN_TILE;
    int t = threadIdx.x;
    int sum = 0;
    #pragma unroll
    for (int j = 0; j < 4; ++j) {
        int i = base + t * 4 + j;
        sum += (i < n) ? deg_i[i] : 0;
    }
    s[t] = sum;
    __syncthreads();
    for (int off = 128; off > 0; off >>= 1) {
        if (t < off) s[t] += s[t + off];
        __syncthreads();
    }
    if (t == 0) bsums[blockIdx.x] = s[0];
}

// Stage 2b: serial scan of 49 tile sums
__global__ void scan2_kernel(const int* __restrict__ bsums,
                             int* __restrict__ bprefix,
                             int* __restrict__ off, int nb, int n)
{
    if (threadIdx.x == 0 && blockIdx.x == 0) {
        int acc = 0;
        for (int i = 0; i < nb; ++i) { bprefix[i] = acc; acc += bsums[i]; }
        off[n] = acc;
    }
}

// Stage 2c: intra-tile exclusive scan -> offsets
__global__ __launch_bounds__(256) void scan3_kernel(
    const int* __restrict__ deg_i, const int* __restrict__ bprefix,
    int* __restrict__ off, int n)
{
    __shared__ int s[256];
    int base = blockIdx.x * SCAN_TILE;
    int t = threadIdx.x;
    int v[4];
    int sum = 0;
    #pragma unroll
    for (int j = 0; j < 4; ++j) {
        int i = base + t * 4 + j;
        v[j] = (i < n) ? deg_i[i] : 0;
        sum += v[j];
    }
    s[t] = sum;
    __syncthreads();
    for (int o = 1; o < 256; o <<= 1) {
        int tmp = (t >= o) ? s[t - o] : 0;
        __syncthreads();
        s[t] += tmp;
        __syncthreads();
    }
    int run = s[t] - sum + bprefix[blockIdx.x];
    #pragma unroll
    for (int j = 0; j < 4; ++j) {
        int i = base + t * 4 + j;
        if (i < n) off[i] = run;
        run += v[j];
    }
}

// Stage 3: atomic-free scatter using precomputed rank
__global__ __launch_bounds__(256) void scatter_kernel(
    const int* __restrict__ src, const int* __restrict__ dst,
    const int* __restrict__ rank, const int* __restrict__ off,
    int* __restrict__ adj, int n_edges)
{
    int e = blockIdx.x * 256 + threadIdx.x;
    if (e >= n_edges) return;
    adj[off[dst[e]] + rank[e]] = src[e];
}

// ---------------------------------------------------------------------------
// Fused gather + linear (round-2 structure, bf16-packed W in 32KB LDS).
// Wave = 4 nodes; lane = feature. Gather: coalesced 256B f32 row reads via
// compile-time readlane broadcast of neighbor ids. Matmul: per k one
// ds_read_b32 yields both output-halves' weights.
// ---------------------------------------------------------------------------
__global__ __launch_bounds__(512, 6) void gather_emb_kernel(
    const float* __restrict__ x,
    const int* __restrict__ adj,
    const int* __restrict__ off,
    const int* __restrict__ deg_i,
    const float* __restrict__ Wn,
    const float* __restrict__ Ws,
    const float* __restrict__ bias,
    float* __restrict__ emb_out)
{
    __shared__ unsigned sWp[128 * 64];   // pack(W[k][lane], W[k][64+lane])
    int t = threadIdx.x;
    for (int i = t; i < 128 * 64; i += 512) {
        int k = i >> 6, lane = i & 63;
        float w0, w1;
        if (k < 64) { w0 = Wn[k * 128 + lane]; w1 = Wn[k * 128 + 64 + lane]; }
        else        { w0 = Ws[(k - 64) * 128 + lane]; w1 = Ws[(k - 64) * 128 + 64 + lane]; }
        sWp[i] = pk_bf16(w0, w1);
    }
    __syncthreads();

    int wave = t >> 6, lane = t & 63;
    int nb = (blockIdx.x * 8 + wave) * 4;
    if (nb >= N_NODES_C) return;

    // gather 4 nodes' neighbor means (lane = feature)
    float a[4];
    #pragma unroll
    for (int i = 0; i < 4; ++i) {
        int node = nb + i;
        int o = off[node];
        int d = deg_i[node];
        float acc = 0.0f;
        for (int j0 = 0; j0 < d; j0 += 64) {
            int c = d - j0; if (c > 64) c = 64;
            int nid = (lane < c) ? adj[o + j0 + lane] : 0;
            int j = 0;
            for (; j + 4 <= c; j += 4) {
                int s0 = bl_i(nid, j + 0);
                int s1 = bl_i(nid, j + 1);
                int s2 = bl_i(nid, j + 2);
                int s3 = bl_i(nid, j + 3);
                float v0 = x[(size_t)s0 * F_IN_C + lane];
                float v1 = x[(size_t)s1 * F_IN_C + lane];
                float v2 = x[(size_t)s2 * F_IN_C + lane];
                float v3 = x[(size_t)s3 * F_IN_C + lane];
                acc += v0; acc += v1; acc += v2; acc += v3;
            }
            for (; j < c; ++j)
                acc += x[(size_t)bl_i(nid, j) * F_IN_C + lane];
        }
        a[i] = acc * (1.0f / fmaxf((float)d, 1.0f));
    }

    float x0 = x[(size_t)(nb + 0) * F_IN_C + lane];
    float x1 = x[(size_t)(nb + 1) * F_IN_C + lane];
    float x2 = x[(size_t)(nb + 2) * F_IN_C + lane];
    float x3 = x[(size_t)(nb + 3) * F_IN_C + lane];

    float bl = bias[lane], bh = bias[64 + lane];
    float al0 = bl, ah0 = bh, al1 = bl, ah1 = bh;
    float al2 = bl, ah2 = bh, al3 = bl, ah3 = bh;

    #pragma unroll
    for (int k = 0; k < 64; ++k) {
        unsigned u = sWp[k * 64 + lane];
        float wlo = __uint_as_float(u << 16);
        float whi = __uint_as_float(u & 0xFFFF0000u);
        float v0 = bl_f(a[0], k);
        float v1 = bl_f(a[1], k);
        float v2 = bl_f(a[2], k);
        float v3 = bl_f(a[3], k);
        al0 += v0 * wlo; ah0 += v0 * whi;
        al1 += v1 * wlo; ah1 += v1 * whi;
        al2 += v2 * wlo; ah2 += v2 * whi;
        al3 += v3 * wlo; ah3 += v3 * whi;
    }
    #pragma unroll
    for (int k = 0; k < 64; ++k) {
        unsigned u = sWp[(64 + k) * 64 + lane];
        float wlo = __uint_as_float(u << 16);
        float whi = __uint_as_float(u & 0xFFFF0000u);
        float v0 = bl_f(x0, k);
        float v1 = bl_f(x1, k);
        float v2 = bl_f(x2, k);
        float v3 = bl_f(x3, k);
        al0 += v0 * wlo; ah0 += v0 * whi;
        al1 += v1 * wlo; ah1 += v1 * whi;
        al2 += v2 * wlo; ah2 += v2 * whi;
        al3 += v3 * wlo; ah3 += v3 * whi;
    }

    emb_out[(size_t)(nb + 0) * HID_C + lane]      = al0;
    emb_out[(size_t)(nb + 0) * HID_C + 64 + lane] = ah0;
    emb_out[(size_t)(nb + 1) * HID_C + lane]      = al1;
    emb_out[(size_t)(nb + 1) * HID_C + 64 + lane] = ah1;
    emb_out[(size_t)(nb + 2) * HID_C + lane]      = al2;
    emb_out[(size_t)(nb + 2) * HID_C + 64 + lane] = ah2;
    emb_out[(size_t)(nb + 3) * HID_C + lane]      = al3;
    emb_out[(size_t)(nb + 3) * HID_C + 64 + lane] = ah3;
}

// ---------------------------------------------------------------------------
// Fused segment mean-pool of relu(emb) + MLP head + log_softmax.
// Block (256 threads) per graph; pool vectorized float4; no atomics.
// ---------------------------------------------------------------------------
__global__ __launch_bounds__(256) void poolhead_kernel(
    const float* __restrict__ emb, const int* __restrict__ start,
    const float* __restrict__ W1, const float* __restrict__ b1,
    const float* __restrict__ W2, const float* __restrict__ b2,
    float* __restrict__ logits_out)
{
    int g = blockIdx.x;
    int t = threadIdx.x;
    __shared__ float sp[HID_C];
    __shared__ float shid[MLP_HID_C];
    __shared__ float sl[N_CLS_C];
    __shared__ float4 red[256];

    int s0 = start[g], e0 = start[g + 1];
    int q = t & 31, r0 = t >> 5;
    const float4* e4 = (const float4*)emb;   // row = 32 float4
    float4 acc = make_float4(0.f, 0.f, 0.f, 0.f);
    for (int r = s0 + r0; r < e0; r += 8) {
        float4 v = e4[(size_t)r * 32 + q];
        acc.x += fmaxf(v.x, 0.f); acc.y += fmaxf(v.y, 0.f);
        acc.z += fmaxf(v.z, 0.f); acc.w += fmaxf(v.w, 0.f);
    }
    red[t] = acc;
    __syncthreads();
    if (t < 32) {
        float4 a = red[t];
        #pragma unroll
        for (int r = 1; r < 8; ++r) {
            float4 b = red[t + 32 * r];
            a.x += b.x; a.y += b.y; a.z += b.z; a.w += b.w;
        }
        float inv = 1.0f / fmaxf((float)(e0 - s0), 1.0f);
        ((float4*)sp)[t] = make_float4(a.x * inv, a.y * inv, a.z * inv, a.w * inv);
    }
    __syncthreads();

    if (t < MLP_HID_C) {
        float a = b1[t];
        #pragma unroll 8
        for (int k = 0; k < HID_C; ++k) a += sp[k] * W1[k * MLP_HID_C + t];
        shid[t] = fmaxf(a, 0.0f);
    }
    __syncthreads();

    if (t < N_CLS_C) {
        float a = b2[t];
        #pragma unroll
        for (int k = 0; k < MLP_HID_C; ++k) a += shid[k] * W2[k * N_CLS_C + t];
        sl[t] = a;
    }
    __syncthreads();

    if (t < N_CLS_C) {
        float m = sl[0];
        #pragma unroll
        for (int i = 1; i < N_CLS_C; ++i) m = fmaxf(m, sl[i]);
        float sum = 0.0f;
        #pragma unroll
        for (int i = 0; i < N_CLS_C; ++i) sum += expf(sl[i] - m);
        logits_out[(size_t)g * N_CLS_C + t] = sl[t] - m - logf(sum);
    }
}

extern "C" void kernel_launch(void* const* d_in, const int* in_sizes, int n_in,
                              void* d_out, int out_size, void* d_ws, size_t ws_size,
                              hipStream_t stream) {
    const float* x      = (const float*)d_in[0];
    const int*   ei     = (const int*)d_in[1];
    const int*   batch  = (const int*)d_in[2];
    const float* Wn     = (const float*)d_in[3];
    const float* Ws     = (const float*)d_in[4];
    const float* bias   = (const float*)d_in[5];
    const float* W1     = (const float*)d_in[6];
    const float* b1     = (const float*)d_in[7];
    const float* W2     = (const float*)d_in[8];
    const float* b2     = (const float*)d_in[9];

    float* out = (float*)d_out;
    int n_edges = in_sizes[1] / 2;
    const int* src = ei;
    const int* dst = ei + n_edges;

    // ws layout (ints): deg_i[N] | off[N+1] | bsums[64] | bprefix[64] |
    //                   start[G+1] | rank[E] | adj[E]
    int* deg_i   = (int*)d_ws;
    int* off     = deg_i + N_NODES_C;
    int* bsums   = off + (N_NODES_C + 1);
    int* bprefix = bsums + 64;
    int* start   = bprefix + 64;
    int* rank    = start + (N_GRAPHS_C + 1);
    int* adj     = rank + n_edges;

    hipMemsetAsync(deg_i, 0, (size_t)N_NODES_C * sizeof(int), stream);

    int eblk = (n_edges + 255) / 256;
    hist_kernel<<<1024, 256, 0, stream>>>(dst, batch, deg_i, rank, start, n_edges);
    scan1_kernel<<<N_SCAN_BLK, 256, 0, stream>>>(deg_i, bsums, N_NODES_C);
    scan2_kernel<<<1, 64, 0, stream>>>(bsums, bprefix, off, N_SCAN_BLK, N_NODES_C);
    scan3_kernel<<<N_SCAN_BLK, 256, 0, stream>>>(deg_i, bprefix, off, N_NODES_C);
    scatter_kernel<<<eblk, 256, 0, stream>>>(src, dst, rank, off, adj, n_edges);

    // 1563 blocks x 8 waves x 4 nodes >= 50000
    gather_emb_kernel<<<1563, 512, 0, stream>>>(x, adj, off, deg_i,
                                                Wn, Ws, bias, out);

    poolhead_kernel<<<N_GRAPHS_C, 256, 0, stream>>>(out, start, W1, b1, W2, b2,
                                                    out + (size_t)N_NODES_C * HID_C);
}

// Round 5
// 133.996 us; speedup vs baseline: 2.7079x; 1.1543x over previous
//
#include <hip/hip_runtime.h>

#define N_NODES_C 50000
#define F_IN_C 64
#define HID_C 128
#define N_GRAPHS_C 500
#define N_CLS_C 10
#define MLP_HID_C 50
#define SCAN_TILE 1024
#define N_SCAN_BLK ((N_NODES_C + SCAN_TILE - 1) / SCAN_TILE)   // 49
#define N_TILES (N_NODES_C / 16)                               // 3125

using short8 = __attribute__((ext_vector_type(8))) short;
using f32x4  = __attribute__((ext_vector_type(4))) float;

__device__ __forceinline__ int bl_i(int v, int l) {
    return __builtin_amdgcn_readlane(v, l);
}
__device__ __forceinline__ float uf(unsigned u) { return __uint_as_float(u); }

// round-to-nearest-even bf16 pack of two floats -> (lo=a, hi=b)
__device__ __forceinline__ unsigned pk_bf16(float a, float b) {
    unsigned ua = __float_as_uint(a), ub = __float_as_uint(b);
    ua += 0x7FFFu + ((ua >> 16) & 1u);
    ub += 0x7FFFu + ((ub >> 16) & 1u);
    return (ua >> 16) | (ub & 0xFFFF0000u);
}

union U8 { unsigned u[4]; short8 s; };

// ---------------------------------------------------------------------------
// Stage 1: degree histogram + per-edge rank (atomic-free scatter later) +
// graph bounds from sorted batch.
// ---------------------------------------------------------------------------
__global__ __launch_bounds__(256) void hist_kernel(
    const int* __restrict__ dst,
    const int* __restrict__ batch,
    int* __restrict__ deg_i,
    int* __restrict__ rank,
    int* __restrict__ start,
    int n_edges)
{
    int tid = blockIdx.x * 256 + threadIdx.x;
    int stride = gridDim.x * 256;
    for (int e = tid; e < n_edges; e += stride)
        rank[e] = atomicAdd(&deg_i[dst[e]], 1);
    for (int i = tid; i < N_NODES_C; i += stride) {
        int b = batch[i];
        if (i == 0) { for (int g = 0; g <= b; ++g) start[g] = 0; }
        else { int p = batch[i - 1]; for (int g = p + 1; g <= b; ++g) start[g] = i; }
        if (i == N_NODES_C - 1) { for (int g = b + 1; g <= N_GRAPHS_C; ++g) start[g] = N_NODES_C; }
    }
}

// Stage 2a: per-1024-tile sums
__global__ __launch_bounds__(256) void scan1_kernel(
    const int* __restrict__ deg_i, int* __restrict__ bsums, int n)
{
    __shared__ int s[256];
    int base = blockIdx.x * SCAN_TILE;
    int t = threadIdx.x;
    int sum = 0;
    #pragma unroll
    for (int j = 0; j < 4; ++j) {
        int i = base + t * 4 + j;
        sum += (i < n) ? deg_i[i] : 0;
    }
    s[t] = sum;
    __syncthreads();
    for (int off = 128; off > 0; off >>= 1) {
        if (t < off) s[t] += s[t + off];
        __syncthreads();
    }
    if (t == 0) bsums[blockIdx.x] = s[0];
}

// Stage 2b (fused): tile-prefix via wave-reduce of bsums + intra-tile scan
__global__ __launch_bounds__(256) void scan3_kernel(
    const int* __restrict__ deg_i, const int* __restrict__ bsums,
    int* __restrict__ off, int n)
{
    __shared__ int s[256];
    __shared__ int sbp;
    int b = blockIdx.x;
    int t = threadIdx.x;
    if (t < 64) {
        int v = (t < b) ? bsums[t] : 0;      // b <= 48 < 64
        #pragma unroll
        for (int m = 1; m < 64; m <<= 1) v += __shfl_xor(v, m, 64);
        if (t == 0) sbp = v;
    }
    int base = b * SCAN_TILE;
    int v4[4];
    int sum = 0;
    #pragma unroll
    for (int j = 0; j < 4; ++j) {
        int i = base + t * 4 + j;
        v4[j] = (i < n) ? deg_i[i] : 0;
        sum += v4[j];
    }
    s[t] = sum;
    __syncthreads();
    for (int o = 1; o < 256; o <<= 1) {
        int tmp = (t >= o) ? s[t - o] : 0;
        __syncthreads();
        s[t] += tmp;
        __syncthreads();
    }
    int run = s[t] - sum + sbp;
    #pragma unroll
    for (int j = 0; j < 4; ++j) {
        int i = base + t * 4 + j;
        if (i < n) off[i] = run;
        run += v4[j];
    }
    if (b == N_SCAN_BLK - 1 && t == 255) off[n] = sbp + s[255];
}

// Stage 3: atomic-free scatter using precomputed rank
__global__ __launch_bounds__(256) void scatter_kernel(
    const int* __restrict__ src, const int* __restrict__ dst,
    const int* __restrict__ rank, const int* __restrict__ off,
    int* __restrict__ adj, int n_edges)
{
    int e = blockIdx.x * 256 + threadIdx.x;
    if (e >= n_edges) return;
    adj[off[dst[e]] + rank[e]] = src[e];
}

// ---------------------------------------------------------------------------
// MFMA GEMM: Y = X @ [Ws | Wn]  (M=50000, K=64, N=256).
// Cols 0..127  (Ws) -> emb_out f32 (+bias).
// Cols 128..255 (Wn) -> yn bf16-packed: yn[row][q] = pack(col q, col q+64).
// W staged bf16-pair-packed (along K) in 32KB LDS; per-tile B frags via ds_read.
// Frag layout: A[lane&15][k=8*(lane>>4)+j]; B[k=8*(lane>>4)+j][lane&15];
// D row=(lane>>4)*4+reg, col=lane&15 (verified).
// ---------------------------------------------------------------------------
__global__ __launch_bounds__(256) void gemm_kernel(
    const float* __restrict__ x,
    const float* __restrict__ Wn,
    const float* __restrict__ Ws,
    const float* __restrict__ bias,
    float* __restrict__ emb_out,
    unsigned* __restrict__ yn)
{
    __shared__ unsigned sWk[32 * 256];   // sWk[m][n] = pack(W256[2m][n], W256[2m+1][n])
    __shared__ float sb[128];
    int t = threadIdx.x;
    for (int e = t; e < 32 * 256; e += 256) {
        int m = e >> 8, n = e & 255;
        float w0, w1;
        if (n < 128) { w0 = Ws[(2 * m) * 128 + n];       w1 = Ws[(2 * m + 1) * 128 + n]; }
        else         { w0 = Wn[(2 * m) * 128 + n - 128]; w1 = Wn[(2 * m + 1) * 128 + n - 128]; }
        sWk[e] = pk_bf16(w0, w1);
    }
    if (t < 128) sb[t] = bias[t];
    __syncthreads();

    int wave = t >> 6, lane = t & 63;
    int lr = lane & 15, lg = lane >> 4;
    int gw = blockIdx.x * 4 + wave;

    for (int tile = gw; tile < N_TILES; tile += 1024) {
        // A frags: row = tile*16 + lr, k = 8*lg + j  (s=0: k 0..31, s=1: k 32..63)
        const float4* xr = (const float4*)(x + ((size_t)tile * 16 + lr) * 64);
        float4 p0 = xr[lg * 2], p1 = xr[lg * 2 + 1];
        float4 p2 = xr[8 + lg * 2], p3 = xr[8 + lg * 2 + 1];
        U8 A0, A1;
        A0.u[0] = pk_bf16(p0.x, p0.y); A0.u[1] = pk_bf16(p0.z, p0.w);
        A0.u[2] = pk_bf16(p1.x, p1.y); A0.u[3] = pk_bf16(p1.z, p1.w);
        A1.u[0] = pk_bf16(p2.x, p2.y); A1.u[1] = pk_bf16(p2.z, p2.w);
        A1.u[2] = pk_bf16(p3.x, p3.y); A1.u[3] = pk_bf16(p3.z, p3.w);

        // f32 half (Ws + bias) -> emb_out
        #pragma unroll
        for (int c = 0; c < 8; ++c) {
            U8 B0, B1;
            #pragma unroll
            for (int jj = 0; jj < 4; ++jj) {
                B0.u[jj] = sWk[(4 * lg + jj) * 256 + c * 16 + lr];
                B1.u[jj] = sWk[(16 + 4 * lg + jj) * 256 + c * 16 + lr];
            }
            float bv = sb[c * 16 + lr];
            f32x4 acc = {bv, bv, bv, bv};
            acc = __builtin_amdgcn_mfma_f32_16x16x32_bf16(A0.s, B0.s, acc, 0, 0, 0);
            acc = __builtin_amdgcn_mfma_f32_16x16x32_bf16(A1.s, B1.s, acc, 0, 0, 0);
            #pragma unroll
            for (int r = 0; r < 4; ++r)
                emb_out[((size_t)tile * 16 + lg * 4 + r) * 128 + c * 16 + lr] = acc[r];
        }
        // bf16 half (Wn) -> yn, pack col pairs (q, q+64)
        #pragma unroll
        for (int cc = 0; cc < 4; ++cc) {
            U8 B0a, B1a, B0b, B1b;
            #pragma unroll
            for (int jj = 0; jj < 4; ++jj) {
                B0a.u[jj] = sWk[(4 * lg + jj) * 256 + (8 + cc) * 16 + lr];
                B1a.u[jj] = sWk[(16 + 4 * lg + jj) * 256 + (8 + cc) * 16 + lr];
                B0b.u[jj] = sWk[(4 * lg + jj) * 256 + (12 + cc) * 16 + lr];
                B1b.u[jj] = sWk[(16 + 4 * lg + jj) * 256 + (12 + cc) * 16 + lr];
            }
            f32x4 aN = {0.f, 0.f, 0.f, 0.f}, aM = {0.f, 0.f, 0.f, 0.f};
            aN = __builtin_amdgcn_mfma_f32_16x16x32_bf16(A0.s, B0a.s, aN, 0, 0, 0);
            aN = __builtin_amdgcn_mfma_f32_16x16x32_bf16(A1.s, B1a.s, aN, 0, 0, 0);
            aM = __builtin_amdgcn_mfma_f32_16x16x32_bf16(A0.s, B0b.s, aM, 0, 0, 0);
            aM = __builtin_amdgcn_mfma_f32_16x16x32_bf16(A1.s, B1b.s, aM, 0, 0, 0);
            #pragma unroll
            for (int r = 0; r < 4; ++r)
                yn[((size_t)tile * 16 + lg * 4 + r) * 64 + cc * 16 + lr] =
                    pk_bf16(aN[r], aM[r]);
        }
    }
}

// ---------------------------------------------------------------------------
// Gather-add: emb_row += mean of neighbors' Yn rows (bf16 u32: cols (l, l+64)).
// Wave = 4 nodes; lane = u32 index. Coalesced 256B row reads; readlane bcast.
// ---------------------------------------------------------------------------
__global__ __launch_bounds__(256) void gather_add_kernel(
    const unsigned* __restrict__ yn,
    const int* __restrict__ adj,
    const int* __restrict__ off,
    float* __restrict__ emb)
{
    int t = threadIdx.x;
    int wave = t >> 6, lane = t & 63;
    int nb = (blockIdx.x * 4 + wave) * 4;
    float ax[4], ay[4];
    #pragma unroll
    for (int i = 0; i < 4; ++i) {
        int node = nb + i;
        int o = off[node];
        int d = off[node + 1] - o;
        float sx = 0.f, sy = 0.f;
        for (int j0 = 0; j0 < d; j0 += 64) {
            int c = d - j0; if (c > 64) c = 64;
            int nid = (lane < c) ? adj[o + j0 + lane] : 0;
            int j = 0;
            for (; j + 4 <= c; j += 4) {
                int s0 = bl_i(nid, j + 0);
                int s1 = bl_i(nid, j + 1);
                int s2 = bl_i(nid, j + 2);
                int s3 = bl_i(nid, j + 3);
                unsigned u0 = yn[(size_t)s0 * 64 + lane];
                unsigned u1 = yn[(size_t)s1 * 64 + lane];
                unsigned u2 = yn[(size_t)s2 * 64 + lane];
                unsigned u3 = yn[(size_t)s3 * 64 + lane];
                sx += uf(u0 << 16); sy += uf(u0 & 0xFFFF0000u);
                sx += uf(u1 << 16); sy += uf(u1 & 0xFFFF0000u);
                sx += uf(u2 << 16); sy += uf(u2 & 0xFFFF0000u);
                sx += uf(u3 << 16); sy += uf(u3 & 0xFFFF0000u);
            }
            for (; j < c; ++j) {
                unsigned u = yn[(size_t)bl_i(nid, j) * 64 + lane];
                sx += uf(u << 16); sy += uf(u & 0xFFFF0000u);
            }
        }
        float inv = 1.0f / fmaxf((float)d, 1.0f);
        ax[i] = sx * inv; ay[i] = sy * inv;
    }
    #pragma unroll
    for (int i = 0; i < 4; ++i) {
        size_t b = (size_t)(nb + i) * 128;
        emb[b + lane]      += ax[i];
        emb[b + 64 + lane] += ay[i];
    }
}

// ---------------------------------------------------------------------------
// Fused segment mean-pool of relu(emb) + MLP head + log_softmax.
// ---------------------------------------------------------------------------
__global__ __launch_bounds__(256) void poolhead_kernel(
    const float* __restrict__ emb, const int* __restrict__ start,
    const float* __restrict__ W1, const float* __restrict__ b1,
    const float* __restrict__ W2, const float* __restrict__ b2,
    float* __restrict__ logits_out)
{
    int g = blockIdx.x;
    int t = threadIdx.x;
    __shared__ float sp[HID_C];
    __shared__ float shid[MLP_HID_C];
    __shared__ float sl[N_CLS_C];
    __shared__ float4 red[256];

    int s0 = start[g], e0 = start[g + 1];
    int q = t & 31, r0 = t >> 5;
    const float4* e4 = (const float4*)emb;
    float4 acc = make_float4(0.f, 0.f, 0.f, 0.f);
    for (int r = s0 + r0; r < e0; r += 8) {
        float4 v = e4[(size_t)r * 32 + q];
        acc.x += fmaxf(v.x, 0.f); acc.y += fmaxf(v.y, 0.f);
        acc.z += fmaxf(v.z, 0.f); acc.w += fmaxf(v.w, 0.f);
    }
    red[t] = acc;
    __syncthreads();
    if (t < 32) {
        float4 a = red[t];
        #pragma unroll
        for (int r = 1; r < 8; ++r) {
            float4 b = red[t + 32 * r];
            a.x += b.x; a.y += b.y; a.z += b.z; a.w += b.w;
        }
        float inv = 1.0f / fmaxf((float)(e0 - s0), 1.0f);
        ((float4*)sp)[t] = make_float4(a.x * inv, a.y * inv, a.z * inv, a.w * inv);
    }
    __syncthreads();

    if (t < MLP_HID_C) {
        float a = b1[t];
        #pragma unroll 8
        for (int k = 0; k < HID_C; ++k) a += sp[k] * W1[k * MLP_HID_C + t];
        shid[t] = fmaxf(a, 0.0f);
    }
    __syncthreads();

    if (t < N_CLS_C) {
        float a = b2[t];
        #pragma unroll
        for (int k = 0; k < MLP_HID_C; ++k) a += shid[k] * W2[k * N_CLS_C + t];
        sl[t] = a;
    }
    __syncthreads();

    if (t < N_CLS_C) {
        float m = sl[0];
        #pragma unroll
        for (int i = 1; i < N_CLS_C; ++i) m = fmaxf(m, sl[i]);
        float sum = 0.0f;
        #pragma unroll
        for (int i = 0; i < N_CLS_C; ++i) sum += expf(sl[i] - m);
        logits_out[(size_t)g * N_CLS_C + t] = sl[t] - m - logf(sum);
    }
}

extern "C" void kernel_launch(void* const* d_in, const int* in_sizes, int n_in,
                              void* d_out, int out_size, void* d_ws, size_t ws_size,
                              hipStream_t stream) {
    const float* x      = (const float*)d_in[0];
    const int*   ei     = (const int*)d_in[1];
    const int*   batch  = (const int*)d_in[2];
    const float* Wn     = (const float*)d_in[3];
    const float* Ws     = (const float*)d_in[4];
    const float* bias   = (const float*)d_in[5];
    const float* W1     = (const float*)d_in[6];
    const float* b1     = (const float*)d_in[7];
    const float* W2     = (const float*)d_in[8];
    const float* b2     = (const float*)d_in[9];

    float* out = (float*)d_out;
    int n_edges = in_sizes[1] / 2;
    const int* src = ei;
    const int* dst = ei + n_edges;

    // ws (ints): deg_i[N] | off[N+1] | bsums[64] | start[G+1] | adj[E] | yn[N*64 u32]
    // rank aliases yn (dead after scatter, before gemm writes yn).
    int* deg_i   = (int*)d_ws;
    int* off     = deg_i + N_NODES_C;
    int* bsums   = off + (N_NODES_C + 1);
    int* start   = bsums + 64;
    int* adj     = start + (N_GRAPHS_C + 1);
    unsigned* yn = (unsigned*)(adj + n_edges);
    int* rank    = (int*)yn;

    hipMemsetAsync(deg_i, 0, (size_t)N_NODES_C * sizeof(int), stream);

    int eblk = (n_edges + 255) / 256;
    hist_kernel<<<1024, 256, 0, stream>>>(dst, batch, deg_i, rank, start, n_edges);
    scan1_kernel<<<N_SCAN_BLK, 256, 0, stream>>>(deg_i, bsums, N_NODES_C);
    scan3_kernel<<<N_SCAN_BLK, 256, 0, stream>>>(deg_i, bsums, off, N_NODES_C);
    scatter_kernel<<<eblk, 256, 0, stream>>>(src, dst, rank, off, adj, n_edges);

    gemm_kernel<<<256, 256, 0, stream>>>(x, Wn, Ws, bias, out, yn);

    // 3125 blocks x 4 waves x 4 nodes = 50000 exactly
    gather_add_kernel<<<3125, 256, 0, stream>>>(yn, adj, off, out);

    poolhead_kernel<<<N_GRAPHS_C, 256, 0, stream>>>(out, start, W1, b1, W2, b2,
                                                    out + (size_t)N_NODES_C * HID_C);
}